// Round 1
// baseline (561.803 us; speedup 1.0000x reference)
//
#include <hip/hip_runtime.h>
#include <cmath>

#define DD 128          // embedding dim
#define TILE_R 64       // rows per GEMM block
#define NEGS 256        // negatives per anchor

// ---------------------------------------------------------------------------
// zero the f64 loss accumulator in workspace
// ---------------------------------------------------------------------------
__global__ void zero_kernel(double* accum) {
    if (threadIdx.x == 0) accum[0] = 0.0;
}

// ---------------------------------------------------------------------------
// Wt[k][c] = W[c][k]  (so GEMM reads of Wt rows are coalesced across lanes)
// ---------------------------------------------------------------------------
__global__ __launch_bounds__(256) void transpose_W(const float* __restrict__ W,
                                                   float* __restrict__ Wt) {
    int e = blockIdx.x * 256 + threadIdx.x;   // grid 64 -> 16384 threads
    int c = e >> 7;
    int k = e & 127;
    Wt[k * DD + c] = W[e];
}

// ---------------------------------------------------------------------------
// emb = X @ W.T + b   (fp32, vector ALU; no fp32 MFMA on CDNA4)
// Block: 256 threads, tile 64 rows x 128 cols. Thread (cg, rg) computes
// 8 rows x 4 cols: rows rg*8..rg*8+7, cols cg*4..cg*4+3.
// X tile staged in LDS (broadcast reads, 2-way bank alias = free).
// Wt rows read from global (coalesced, L1/L2-resident 64 KB).
// ---------------------------------------------------------------------------
__global__ __launch_bounds__(256) void linear_kernel(const float* __restrict__ X,
                                                     const float* __restrict__ Wt,
                                                     const float* __restrict__ b,
                                                     float* __restrict__ Y,
                                                     int N) {
    __shared__ float xs[TILE_R][DD];

    const int t  = threadIdx.x;
    const int cg = t & 31;   // col group -> cols cg*4 .. cg*4+3
    const int rg = t >> 5;   // row group -> rows rg*8 .. rg*8+7
    const int r0 = blockIdx.x * TILE_R;

    // ---- stage X tile (coalesced float4) ----
    const float4* X4  = (const float4*)X;
    float4*       xs4 = (float4*)&xs[0][0];
    #pragma unroll
    for (int i = 0; i < 8; ++i) {
        int q   = i * 256 + t;            // 0..2047 float4 slots
        int row = r0 + (q >> 5);
        float4 v = make_float4(0.f, 0.f, 0.f, 0.f);
        if (row < N) v = X4[(size_t)row * 32 + (q & 31)];
        xs4[q] = v;
    }

    // ---- init accumulators with bias ----
    float4 bv = ((const float4*)b)[cg];
    float acc[8][4];
    #pragma unroll
    for (int j = 0; j < 8; ++j) {
        acc[j][0] = bv.x; acc[j][1] = bv.y; acc[j][2] = bv.z; acc[j][3] = bv.w;
    }
    __syncthreads();

    // ---- main k loop ----
    #pragma unroll 8
    for (int k = 0; k < DD; ++k) {
        float4 w = ((const float4*)(Wt + (size_t)k * DD))[cg];
        float xv[8];
        #pragma unroll
        for (int j = 0; j < 8; ++j) xv[j] = xs[rg * 8 + j][k];
        #pragma unroll
        for (int j = 0; j < 8; ++j) {
            acc[j][0] += xv[j] * w.x;
            acc[j][1] += xv[j] * w.y;
            acc[j][2] += xv[j] * w.z;
            acc[j][3] += xv[j] * w.w;
        }
    }

    // ---- store (coalesced float4) ----
    #pragma unroll
    for (int j = 0; j < 8; ++j) {
        int row = r0 + rg * 8 + j;
        if (row < N) {
            float4 o = make_float4(acc[j][0], acc[j][1], acc[j][2], acc[j][3]);
            ((float4*)(Y + (size_t)row * DD))[cg] = o;
        }
    }
}

// ---------------------------------------------------------------------------
// One block per (branch, p). 256 threads: thread t owns negative t.
// q staged in LDS; per-thread full-row float4 dot (gathers are L3-served).
// Block-wide logsumexp, then one f64 atomic per block.
// ---------------------------------------------------------------------------
__global__ __launch_bounds__(256) void ntxent_kernel(
        const float* __restrict__ emb,
        const int* __restrict__ anchor0, const int* __restrict__ partner0,
        const int* __restrict__ negidx0,
        const int* __restrict__ anchor1, const int* __restrict__ partner1,
        const int* __restrict__ negidx1,
        double* __restrict__ accum, int P) {
    const int bp     = blockIdx.x;
    const int branch = (bp >= P) ? 1 : 0;
    const int p      = branch ? (bp - P) : bp;

    const int* anchor  = branch ? anchor1  : anchor0;
    const int* partner = branch ? partner1 : partner0;
    const int* negidx  = branch ? negidx1  : negidx0;
    const float scale  = (branch ? 0.1f : 1.0f) / (float)P;
    const float INV_T  = 1.0f / 0.07f;

    __shared__ float4 qs[32];
    __shared__ float  sh_lpos;
    __shared__ float  wred[4];
    __shared__ float  wsum[4];

    const int t = threadIdx.x;
    const float4* emb4 = (const float4*)emb;

    const int aidx = anchor[p];
    const int kidx = partner[p];

    if (t < 32) qs[t] = emb4[(size_t)aidx * 32 + t];
    __syncthreads();

    // ---- l_pos via wave 0 (lanes 0..31 hold partials, rest contribute 0) ----
    if (t < 64) {
        float part = 0.f;
        if (t < 32) {
            float4 qv = qs[t];
            float4 kv = emb4[(size_t)kidx * 32 + t];
            part = qv.x * kv.x + qv.y * kv.y + qv.z * kv.z + qv.w * kv.w;
        }
        #pragma unroll
        for (int m = 32; m >= 1; m >>= 1) part += __shfl_xor(part, m, 64);
        if (t == 0) sh_lpos = part;
    }

    // ---- negative dot: thread t handles neg t ----
    const int idx = negidx[(size_t)p * NEGS + t];
    const float4* row = emb4 + (size_t)idx * 32;
    float acc = 0.f;
    #pragma unroll
    for (int kk = 0; kk < 32; ++kk) {
        float4 qv = qs[kk];
        float4 rv = row[kk];
        acc += qv.x * rv.x + qv.y * rv.y + qv.z * rv.z + qv.w * rv.w;
    }
    __syncthreads();   // sh_lpos visible; qs no longer needed

    const float zpos = sh_lpos * INV_T;
    const float z    = acc * INV_T;

    // ---- block max over 257 logits ----
    float m = (t == 0) ? fmaxf(z, zpos) : z;
    #pragma unroll
    for (int s = 32; s >= 1; s >>= 1) m = fmaxf(m, __shfl_xor(m, s, 64));
    if ((t & 63) == 0) wred[t >> 6] = m;
    __syncthreads();
    m = fmaxf(fmaxf(wred[0], wred[1]), fmaxf(wred[2], wred[3]));

    // ---- block sum of exp(z - m) (pos term added by thread 0) ----
    float e = expf(z - m);
    if (t == 0) e += expf(zpos - m);
    #pragma unroll
    for (int s = 32; s >= 1; s >>= 1) e += __shfl_xor(e, s, 64);
    if ((t & 63) == 0) wsum[t >> 6] = e;
    __syncthreads();

    if (t == 0) {
        float S    = wsum[0] + wsum[1] + wsum[2] + wsum[3];
        float loss = m + logf(S) - zpos;     // lse - l_pos/T
        atomicAdd(accum, (double)(loss * scale));
    }
}

// ---------------------------------------------------------------------------
__global__ void finalize_kernel(const double* __restrict__ accum,
                                float* __restrict__ out) {
    if (threadIdx.x == 0) out[0] = (float)accum[0];
}

// ---------------------------------------------------------------------------
extern "C" void kernel_launch(void* const* d_in, const int* in_sizes, int n_in,
                              void* d_out, int out_size, void* d_ws, size_t ws_size,
                              hipStream_t stream) {
    const float* embeddings  = (const float*)d_in[0];
    const float* W           = (const float*)d_in[1];
    const float* b           = (const float*)d_in[2];
    const int*   pos_anchor  = (const int*)d_in[3];
    const int*   pos_partner = (const int*)d_in[4];
    const int*   neg_idx     = (const int*)d_in[5];
    const int*   weak_anchor  = (const int*)d_in[6];
    const int*   weak_partner = (const int*)d_in[7];
    const int*   weak_neg_idx = (const int*)d_in[8];
    float* out = (float*)d_out;

    const int N = in_sizes[0] / DD;        // 100000
    const int P = in_sizes[3];             // 8192

    // workspace layout: [0,256) f64 accum | [256, 256+64K) Wt | then emb
    char*   ws    = (char*)d_ws;
    double* accum = (double*)ws;
    float*  Wt    = (float*)(ws + 256);
    float*  emb   = (float*)(ws + 256 + DD * DD * sizeof(float));

    zero_kernel<<<1, 64, 0, stream>>>(accum);
    transpose_W<<<DD * DD / 256, 256, 0, stream>>>(W, Wt);

    const int tiles = (N + TILE_R - 1) / TILE_R;
    linear_kernel<<<tiles, 256, 0, stream>>>(embeddings, Wt, b, emb, N);

    ntxent_kernel<<<2 * P, 256, 0, stream>>>(emb,
                                             pos_anchor, pos_partner, neg_idx,
                                             weak_anchor, weak_partner, weak_neg_idx,
                                             accum, P);

    finalize_kernel<<<1, 64, 0, stream>>>(accum, out);
}

// Round 3
// 472.423 us; speedup vs baseline: 1.1892x; 1.1892x over previous
//
#include <hip/hip_runtime.h>
#include <cmath>

#define DD 128          // embedding dim
#define TILE_R 64       // rows per GEMM block
#define NEGS 256        // negatives per anchor

// ---------------------------------------------------------------------------
// zero the f64 loss accumulator in workspace
// ---------------------------------------------------------------------------
__global__ void zero_kernel(double* accum) {
    if (threadIdx.x == 0) accum[0] = 0.0;
}

// ---------------------------------------------------------------------------
// Wt[k][c] = W[c][k]
// ---------------------------------------------------------------------------
__global__ __launch_bounds__(256) void transpose_W(const float* __restrict__ W,
                                                   float* __restrict__ Wt) {
    int e = blockIdx.x * 256 + threadIdx.x;
    int c = e >> 7;
    int k = e & 127;
    Wt[k * DD + c] = W[e];
}

// ---------------------------------------------------------------------------
// emb = X @ W.T + b   (fp32 vector ALU). 256 thr, tile 64 rows x 128 cols.
// Thread (cg,rg): 8 rows x 4 cols. X tile in LDS, read as float4 (b128,
// broadcast across half-wave). Wt rows from global (L1/L2-hot 64 KB).
// ---------------------------------------------------------------------------
__global__ __launch_bounds__(256) void linear_kernel(const float* __restrict__ X,
                                                     const float* __restrict__ Wt,
                                                     const float* __restrict__ b,
                                                     float* __restrict__ Y,
                                                     int N) {
    __shared__ __align__(16) float xs[TILE_R][DD];

    const int t  = threadIdx.x;
    const int cg = t & 31;   // cols cg*4 .. cg*4+3
    const int rg = t >> 5;   // rows rg*8 .. rg*8+7
    const int r0 = blockIdx.x * TILE_R;

    // stage X tile (coalesced float4)
    const float4* X4  = (const float4*)X;
    float4*       xs4 = (float4*)&xs[0][0];
    #pragma unroll
    for (int i = 0; i < 8; ++i) {
        int q   = i * 256 + t;
        int row = r0 + (q >> 5);
        float4 v = make_float4(0.f, 0.f, 0.f, 0.f);
        if (row < N) v = X4[(size_t)row * 32 + (q & 31)];
        xs4[q] = v;
    }

    float4 bv = ((const float4*)b)[cg];
    float acc[8][4];
    #pragma unroll
    for (int j = 0; j < 8; ++j) {
        acc[j][0] = bv.x; acc[j][1] = bv.y; acc[j][2] = bv.z; acc[j][3] = bv.w;
    }
    __syncthreads();

    // k loop in chunks of 4, float4 LDS reads
    #pragma unroll 4
    for (int kc = 0; kc < DD / 4; ++kc) {
        float4 xv[8];
        #pragma unroll
        for (int j = 0; j < 8; ++j)
            xv[j] = *(const float4*)&xs[rg * 8 + j][kc * 4];
        #pragma unroll
        for (int kk = 0; kk < 4; ++kk) {
            float4 w = ((const float4*)(Wt + (size_t)(kc * 4 + kk) * DD))[cg];
            #pragma unroll
            for (int j = 0; j < 8; ++j) {
                float xk = (kk == 0) ? xv[j].x : (kk == 1) ? xv[j].y
                         : (kk == 2) ? xv[j].z : xv[j].w;
                acc[j][0] += xk * w.x;
                acc[j][1] += xk * w.y;
                acc[j][2] += xk * w.z;
                acc[j][3] += xk * w.w;
            }
        }
    }

    #pragma unroll
    for (int j = 0; j < 8; ++j) {
        int row = r0 + rg * 8 + j;
        if (row < N) {
            float4 o = make_float4(acc[j][0], acc[j][1], acc[j][2], acc[j][3]);
            ((float4*)(Y + (size_t)row * DD))[cg] = o;
        }
    }
}

// ---------------------------------------------------------------------------
// One block per (branch, p). 256 threads = 4 waves; each wave owns 64 negs.
// Cooperative gather: 8 lanes per row -> each load instr covers 8 rows x
// 128 B contiguous (full sectors, no L1-thrash amplification).
// Group dot: 4 float4 FMA + 3-step shfl_xor. Then block logsumexp.
// ---------------------------------------------------------------------------
__global__ __launch_bounds__(256) void ntxent_kernel(
        const float* __restrict__ emb,
        const int* __restrict__ anchor0, const int* __restrict__ partner0,
        const int* __restrict__ negidx0,
        const int* __restrict__ anchor1, const int* __restrict__ partner1,
        const int* __restrict__ negidx1,
        double* __restrict__ accum, int P) {
    const int bp     = blockIdx.x;
    const int branch = (bp >= P) ? 1 : 0;
    const int p      = branch ? (bp - P) : bp;

    const int* anchor  = branch ? anchor1  : anchor0;
    const int* partner = branch ? partner1 : partner0;
    const int* negidx  = branch ? negidx1  : negidx0;
    const float scale  = (branch ? 0.1f : 1.0f) / (float)P;
    const float INV_T  = 1.0f / 0.07f;

    __shared__ float4 qs[32];
    __shared__ float  sh_lpos;
    __shared__ float  wred[4];
    __shared__ float  wsum[4];

    const int t    = threadIdx.x;
    const int wave = t >> 6;
    const int lane = t & 63;
    const int grp  = lane >> 3;   // 8 groups of 8 lanes
    const int j    = lane & 7;

    const float4* emb4 = (const float4*)emb;

    const int aidx = anchor[p];
    const int kidx = partner[p];

    if (t < 32) qs[t] = emb4[(size_t)aidx * 32 + t];
    __syncthreads();

    // ---- l_pos on wave 0 ----
    if (t < 64) {
        float part = 0.f;
        if (t < 32) {
            float4 qv = qs[t];
            float4 kv = emb4[(size_t)kidx * 32 + t];
            part = qv.x * kv.x + qv.y * kv.y + qv.z * kv.z + qv.w * kv.w;
        }
        #pragma unroll
        for (int m = 32; m >= 1; m >>= 1) part += __shfl_xor(part, m, 64);
        if (t == 0) sh_lpos = part;
    }

    // ---- q fragments for this lane: q4 positions {j, 8+j, 16+j, 24+j} ----
    float4 qf[4];
    #pragma unroll
    for (int i = 0; i < 4; ++i) qf[i] = qs[i * 8 + j];

    // ---- negative dots: wave's 64 indices loaded coalesced, shfl-dist ----
    const int nbase   = wave * 64;
    const int idx_own = negidx[(size_t)p * NEGS + nbase + lane];

    float zreg[8];
    #pragma unroll
    for (int pi = 0; pi < 8; ++pi) {
        int nidx = __shfl(idx_own, pi * 8 + grp, 64);
        const float4* row = emb4 + (size_t)nidx * 32;
        float partial = 0.f;
        #pragma unroll
        for (int i = 0; i < 4; ++i) {
            float4 rv = row[i * 8 + j];
            float4 qv = qf[i];
            partial += qv.x * rv.x + qv.y * rv.y + qv.z * rv.z + qv.w * rv.w;
        }
        partial += __shfl_xor(partial, 1, 64);
        partial += __shfl_xor(partial, 2, 64);
        partial += __shfl_xor(partial, 4, 64);
        zreg[pi] = partial * INV_T;   // all 8 lanes of group hold row's z
    }

    __syncthreads();   // sh_lpos visible
    const float zpos = sh_lpos * INV_T;

    // ---- block max over 257 logits (replication is harmless for max) ----
    float m = zreg[0];
    #pragma unroll
    for (int pi = 1; pi < 8; ++pi) m = fmaxf(m, zreg[pi]);
    if (t == 0) m = fmaxf(m, zpos);
    #pragma unroll
    for (int s = 32; s >= 1; s >>= 1) m = fmaxf(m, __shfl_xor(m, s, 64));
    if (lane == 0) wred[wave] = m;
    __syncthreads();
    m = fmaxf(fmaxf(wred[0], wred[1]), fmaxf(wred[2], wred[3]));

    // ---- block sum of exp (only j==0 lanes contribute, kills replication) --
    float e = 0.f;
    if (j == 0) {
        #pragma unroll
        for (int pi = 0; pi < 8; ++pi) e += expf(zreg[pi] - m);
    }
    if (t == 0) e += expf(zpos - m);
    #pragma unroll
    for (int s = 32; s >= 1; s >>= 1) e += __shfl_xor(e, s, 64);
    if (lane == 0) wsum[wave] = e;
    __syncthreads();

    if (t == 0) {
        float S    = wsum[0] + wsum[1] + wsum[2] + wsum[3];
        float loss = m + logf(S) - zpos;
        atomicAdd(accum, (double)(loss * scale));
    }
}

// ---------------------------------------------------------------------------
__global__ void finalize_kernel(const double* __restrict__ accum,
                                float* __restrict__ out) {
    if (threadIdx.x == 0) out[0] = (float)accum[0];
}

// ---------------------------------------------------------------------------
extern "C" void kernel_launch(void* const* d_in, const int* in_sizes, int n_in,
                              void* d_out, int out_size, void* d_ws, size_t ws_size,
                              hipStream_t stream) {
    const float* embeddings  = (const float*)d_in[0];
    const float* W           = (const float*)d_in[1];
    const float* b           = (const float*)d_in[2];
    const int*   pos_anchor  = (const int*)d_in[3];
    const int*   pos_partner = (const int*)d_in[4];
    const int*   neg_idx     = (const int*)d_in[5];
    const int*   weak_anchor  = (const int*)d_in[6];
    const int*   weak_partner = (const int*)d_in[7];
    const int*   weak_neg_idx = (const int*)d_in[8];
    float* out = (float*)d_out;

    const int N = in_sizes[0] / DD;        // 100000
    const int P = in_sizes[3];             // 8192

    char*   ws    = (char*)d_ws;
    double* accum = (double*)ws;
    float*  Wt    = (float*)(ws + 256);
    float*  emb   = (float*)(ws + 256 + DD * DD * sizeof(float));

    zero_kernel<<<1, 64, 0, stream>>>(accum);
    transpose_W<<<DD * DD / 256, 256, 0, stream>>>(W, Wt);

    const int tiles = (N + TILE_R - 1) / TILE_R;
    linear_kernel<<<tiles, 256, 0, stream>>>(embeddings, Wt, b, emb, N);

    ntxent_kernel<<<2 * P, 256, 0, stream>>>(emb,
                                             pos_anchor, pos_partner, neg_idx,
                                             weak_anchor, weak_partner, weak_neg_idx,
                                             accum, P);

    finalize_kernel<<<1, 64, 0, stream>>>(accum, out);
}